// Round 8
// baseline (557.296 us; speedup 1.0000x reference)
//
#include <hip/hip_runtime.h>
#include <hip/hip_bf16.h>

#define N_NODES  100000
#define N_EDGES  1600000
#define N_GRAPHS 256
#define DCH      128
#define DOUT     64
#define NBK      391      // buckets / rowcur blocks = ceil(100000/256)
#define DEGPAD   100096   // 391*256
#define PADB     512

typedef short v8s __attribute__((ext_vector_type(8)));
typedef float v4f __attribute__((ext_vector_type(4)));

static __device__ __forceinline__ float bf2f(unsigned short u) {
    unsigned int x = ((unsigned int)u) << 16;
    return __builtin_bit_cast(float, x);
}
static __device__ __forceinline__ unsigned short f2bf(float f) {
    unsigned int x = __builtin_bit_cast(unsigned int, f);
    unsigned int r = (x + 0x7fffu + ((x >> 16) & 1u)) >> 16;
    return (unsigned short)r;
}
static __device__ __forceinline__ int clampi(int v, int lo, int hi) {
    return v < lo ? lo : (v > hi ? hi : v);
}

// ---------------- CSR step 1: degree count (global atomics) + bucket sums ----------------
// 782 blocks x 2048 edges. deg/bsum zeroed by the preceding memset.
// Per-address contention on deg = avg degree 16 over the whole pass: negligible.
// Bucket sums via LDS histogram -> one global atomicAdd per non-empty bucket per block.
__global__ void __launch_bounds__(256) deg_kernel(const int* __restrict__ dst,
                                                  int* __restrict__ deg, int* __restrict__ bsum) {
    __shared__ int hcnt[PADB];
    int tid = threadIdx.x;
    int e0  = blockIdx.x * 2048;
    for (int b = tid; b < PADB; b += 256) hcnt[b] = 0;
    __syncthreads();
    #pragma unroll
    for (int j = 0; j < 8; j++) {
        int e = e0 + j * 256 + tid;
        if (e < N_EDGES) {
            int d = clampi(dst[e], 0, N_NODES - 1);
            atomicAdd(&deg[d], 1);
            atomicAdd(&hcnt[d >> 8], 1);
        }
    }
    __syncthreads();
    for (int b = tid; b < PADB; b += 256) {
        int c = hcnt[b];
        if (c > 0) atomicAdd(&bsum[b], c);
    }
}

// ---------------- CSR step 2: rowptr + scatter cursors ----------------
// 391 blocks; each block redundantly scans bsum[512] (proven binFinish pattern),
// then local-scans its 256 degrees -> rowptr[node] and cur[node].
__global__ void __launch_bounds__(256) rowcur_kernel(const int* __restrict__ bsum, const int* __restrict__ deg,
                                                     int* __restrict__ rowptr, int* __restrict__ cur) {
    __shared__ int s2[256], sc[256], hoff[PADB];
    int b = blockIdx.x, tid = threadIdx.x;
    int c0 = bsum[2 * tid], c1 = bsum[2 * tid + 1];
    s2[tid] = c0 + c1;
    __syncthreads();
    for (int off = 1; off < 256; off <<= 1) {
        int xx = (tid >= off) ? s2[tid - off] : 0;
        __syncthreads();
        s2[tid] += xx;
        __syncthreads();
    }
    int excl = s2[tid] - (c0 + c1);
    hoff[2 * tid] = excl; hoff[2 * tid + 1] = excl + c0;
    __syncthreads();
    if (b == 0 && tid == 255) rowptr[N_NODES] = s2[255];   // total = N_EDGES (pad degs are 0)
    int base = hoff[b];
    int node = b * 256 + tid;                              // < DEGPAD always
    int d = deg[node];
    sc[tid] = d;
    __syncthreads();
    for (int off = 1; off < 256; off <<= 1) {
        int xx = (tid >= off) ? sc[tid - off] : 0;
        __syncthreads();
        sc[tid] += xx;
        __syncthreads();
    }
    int myptr = base + sc[tid] - d;
    if (node < N_NODES) rowptr[node] = myptr;
    cur[node] = myptr;
}

// ---------------- CSR step 3 + prep, one dispatch ----------------
// bid < 1563: edge scatter csr[atomicAdd(cur[dst])] = src (order within node arbitrary).
// remaining 12549 blocks: cvt (fp32->bf16 features), weight fragments, zero rows.
__global__ void __launch_bounds__(256) scatPrep_kernel(
    const int* __restrict__ src, const int* __restrict__ dst,
    int* __restrict__ cur, int* __restrict__ csr,
    const float* __restrict__ x, unsigned short* __restrict__ B2,
    const float* __restrict__ W1rel, const float* __restrict__ W1root,
    const float* __restrict__ W2rel, const float* __restrict__ W2root,
    const float* __restrict__ W3rel, const float* __restrict__ W3root,
    unsigned short* __restrict__ frag,
    unsigned short* __restrict__ z1, unsigned short* __restrict__ z2)
{
    int tid = threadIdx.x;
    if (blockIdx.x < 1563) {                 // scatter: 1563*1024 >= N_EDGES
        int e0 = blockIdx.x * 1024;
        #pragma unroll
        for (int j = 0; j < 4; j++) {
            int e = e0 + j * 256 + tid;
            if (e < N_EDGES) {
                int d = clampi(dst[e], 0, N_NODES - 1);
                int s = clampi(src[e], 0, N_NODES - 1);
                int p = atomicAdd(&cur[d], 1);
                csr[p] = s;
            }
        }
        return;
    }
    int bid = blockIdx.x - 1563;
    if (bid < 12500) {                       // cvt: 12500*256*4 == N_NODES*DCH exactly
        size_t i = ((size_t)bid * 256 + tid) * 4;
        float4 f = *reinterpret_cast<const float4*>(x + i);
        uint2 o;
        o.x = ((unsigned)f2bf(f.y) << 16) | (unsigned)f2bf(f.x);
        o.y = ((unsigned)f2bf(f.w) << 16) | (unsigned)f2bf(f.z);
        *reinterpret_cast<uint2*>(B2 + i) = o;
    } else if (bid < 12548) {                // wfrag: 48*256 == 12288 == 3*8*8*64
        int gid = (bid - 12500) * 256 + tid;
        int lane = gid & 63;
        int nt   = (gid >> 6) & 7;
        int kt   = (gid >> 9) & 7;
        int L    = gid >> 12;
        const float* rel  = (L == 0) ? W1rel  : (L == 1) ? W2rel  : W3rel;
        const float* root = (L == 0) ? W1root : (L == 1) ? W2root : W3root;
        int n  = nt * 16 + (lane & 15);
        int k0 = kt * 32 + (lane >> 4) * 8;
        unsigned short o[8];
        #pragma unroll
        for (int j = 0; j < 8; j++) {
            int k = k0 + j;
            float w = (k < 128) ? rel[k * 128 + n] : root[(k - 128) * 128 + n];
            o[j] = f2bf(w);
        }
        uint4 u;
        u.x = (unsigned)o[0] | ((unsigned)o[1] << 16);
        u.y = (unsigned)o[2] | ((unsigned)o[3] << 16);
        u.z = (unsigned)o[4] | ((unsigned)o[5] << 16);
        u.w = (unsigned)o[6] | ((unsigned)o[7] << 16);
        *reinterpret_cast<uint4*>(frag + (size_t)gid * 8) = u;
    } else {                                 // zero rows (gather target for padded lanes)
        if (tid < 64)       reinterpret_cast<unsigned*>(z1)[tid] = 0;
        else if (tid < 128) reinterpret_cast<unsigned*>(z2)[tid - 64] = 0;
    }
}

// ---------------- fused layer: block-level agg (4 waves x 4 nodes) + MFMA tail ----------------
// Unchanged from r7 (best measured: 74 us/layer, gather at the r6-proven shape).
__global__ void __launch_bounds__(256, 6) layer_kernel(
    const unsigned short* __restrict__ hin,   // N_NODES+1 rows; row N_NODES is zero
    const int* __restrict__ rowptr, const int* __restrict__ csr,
    const unsigned short* __restrict__ frag, const float* __restrict__ bias,
    unsigned short* __restrict__ hout,        // != hin (ping-pong; unused for mode 2)
    const int* __restrict__ batch, float* __restrict__ psum, int mode)
{
    __shared__ __attribute__((aligned(16))) unsigned short As[16 * DCH];  // 4 KB
    const int wave = threadIdx.x >> 6;
    const int lane = threadIdx.x & 63;
    const int l16  = lane & 15;
    const int quad = lane >> 4;
    const int base = blockIdx.x * 16;
    char* Asb = reinterpret_cast<char*>(As);

    // ---------- aggregation: 4 independent per-node loops ----------
    #pragma unroll
    for (int k = 0; k < 4; k++) {
        const int row  = wave * 4 + k;
        const int node = base + row;
        const int r0 = rowptr[node];          // wave-uniform -> scalar loads
        const int r1 = rowptr[node + 1];
        float a0 = 0.f, a1 = 0.f;
        int t = csr[r0 + l16];                // csr over-allocated: overread safe
        for (int c = r0; c < r1; c += 16) {
            int tn = csr[c + 16 + l16];       // prefetch next chunk
            int idx = (c + l16 < r1) ? t : N_NODES;
            #pragma unroll
            for (int j = 0; j < 16; j++) {
                int s = __builtin_amdgcn_readlane(idx, j);   // SGPR row index -> saddr gather
                unsigned v = *reinterpret_cast<const unsigned*>(hin + (size_t)s * DCH + lane * 2);
                a0 += bf2f((unsigned short)(v & 0xffffu));   // padded lanes hit the zero row
                a1 += bf2f((unsigned short)(v >> 16));
            }
            t = tn;
        }
        int deg = r1 - r0;
        float inv = 1.0f / (float)(deg > 1 ? deg : 1);
        unsigned o = ((unsigned)f2bf(a1 * inv) << 16) | (unsigned)f2bf(a0 * inv);
        *reinterpret_cast<unsigned*>(Asb + row * 256 + ((lane * 4) ^ ((row & 7) << 4))) = o;
    }
    __syncthreads();

    // ---------- MFMA tail: wave w -> nt = 2w, 2w+1 ----------
    const int nt0 = wave * 2;
    v4f acc0 = (v4f){0.f, 0.f, 0.f, 0.f};
    v4f acc1 = (v4f){0.f, 0.f, 0.f, 0.f};
    #pragma unroll
    for (int kt = 0; kt < 8; kt++) {
        v8s av;
        if (kt < 4) {
            int co = (kt * 64 + quad * 16) ^ ((l16 & 7) << 4);
            av = *reinterpret_cast<const v8s*>(Asb + l16 * 256 + co);
        } else {
            int ak = (kt - 4) * 32 + quad * 8;
            av = *reinterpret_cast<const v8s*>(hin + (size_t)(base + l16) * DCH + ak);
        }
        v8s b0 = *reinterpret_cast<const v8s*>(frag + (((size_t)(kt * 8 + nt0)) * 64 + lane) * 8);
        v8s b1 = *reinterpret_cast<const v8s*>(frag + (((size_t)(kt * 8 + nt0 + 1)) * 64 + lane) * 8);
        acc0 = __builtin_amdgcn_mfma_f32_16x16x32_bf16(av, b0, acc0, 0, 0, 0);
        acc1 = __builtin_amdgcn_mfma_f32_16x16x32_bf16(av, b1, acc1, 0, 0, 0);
    }

    const int n0 = nt0 * 16 + l16;
    const int n1 = n0 + 16;
    const float bv0 = bias[n0];
    const float bv1 = bias[n1];

    if (mode != 2) {
        #pragma unroll
        for (int r = 0; r < 4; r++) {
            int row = base + quad * 4 + r;    // always < N_NODES (exact tiling)
            float x0 = acc0[r] + bv0;
            float x1 = acc1[r] + bv1;
            if (mode == 1) { x0 = fmaxf(x0, 0.f); x1 = fmaxf(x1, 0.f); }
            hout[(size_t)row * DCH + n0] = f2bf(x0);
            hout[(size_t)row * DCH + n1] = f2bf(x1);
        }
    } else {
        // pooled epilogue: per-graph column sums (mean + matvec in final_kernel)
        bool fast = (batch[base] == batch[base + 15]);
        if (fast) {
            int g = batch[base];              // all 16 rows same graph (~94% of blocks)
            float s0 = acc0[0] + acc0[1] + acc0[2] + acc0[3] + 4.0f * bv0;
            float s1 = acc1[0] + acc1[1] + acc1[2] + acc1[3] + 4.0f * bv1;
            s0 += __shfl_xor(s0, 16); s0 += __shfl_xor(s0, 32);
            s1 += __shfl_xor(s1, 16); s1 += __shfl_xor(s1, 32);
            if (quad == 0) {
                atomicAdd(&psum[g * DCH + n0], s0);
                atomicAdd(&psum[g * DCH + n1], s1);
            }
        } else {
            int g[4];
            #pragma unroll
            for (int r = 0; r < 4; r++) g[r] = batch[base + quad * 4 + r];
            float s0 = 0.f, s1 = 0.f; int cg = -1;
            #pragma unroll
            for (int r = 0; r < 4; r++) {
                if (g[r] != cg) {
                    if (cg >= 0) {
                        atomicAdd(&psum[cg * DCH + n0], s0);
                        atomicAdd(&psum[cg * DCH + n1], s1);
                    }
                    s0 = 0.f; s1 = 0.f; cg = g[r];
                }
                s0 += acc0[r] + bv0;
                s1 += acc1[r] + bv1;
            }
            if (cg >= 0) {
                atomicAdd(&psum[cg * DCH + n0], s0);
                atomicAdd(&psum[cg * DCH + n1], s1);
            }
        }
    }
}

// ---------------- final: out[g] = (psum[g]/cnt_g) @ Wl + bl ----------------
static __device__ __forceinline__ int lowerb(const int* __restrict__ a, int n, int key) {
    int lo = 0, hi = n;
    while (lo < hi) { int mid = (lo + hi) >> 1; if (a[mid] < key) lo = mid + 1; else hi = mid; }
    return lo;
}

__global__ void __launch_bounds__(64) final_kernel(const float* __restrict__ psum,
                                                   const int* __restrict__ batch,
                                                   const float* __restrict__ Wl, const float* __restrict__ bl,
                                                   float* __restrict__ out) {
    __shared__ float ps[DCH];
    __shared__ int bounds[2];
    int g = blockIdx.x, tid = threadIdx.x;
    if (tid == 0) {
        bounds[0] = lowerb(batch, N_NODES, g);
        bounds[1] = lowerb(batch, N_NODES, g + 1);
    }
    __syncthreads();
    int cnt = bounds[1] - bounds[0];
    float inv = 1.0f / (float)(cnt > 1 ? cnt : 1);
    ps[tid] = psum[g * DCH + tid] * inv;
    ps[tid + 64] = psum[g * DCH + tid + 64] * inv;
    __syncthreads();
    float o = 0.f;
    #pragma unroll 4
    for (int c = 0; c < DCH; c++) o += ps[c] * Wl[c * DOUT + tid];
    out[g * DOUT + tid] = o + bl[tid];
}

extern "C" void kernel_launch(void* const* d_in, const int* in_sizes, int n_in,
                              void* d_out, int out_size, void* d_ws, size_t ws_size,
                              hipStream_t stream) {
    const float* x     = (const float*)d_in[0];
    const int*   edge  = (const int*)d_in[1];
    const int*   src   = edge;
    const int*   dst   = edge + N_EDGES;
    const int*   batch = (const int*)d_in[2];
    const float* W1rel  = (const float*)d_in[3];
    const float* b1     = (const float*)d_in[4];
    const float* W1root = (const float*)d_in[5];
    const float* W2rel  = (const float*)d_in[6];
    const float* b2     = (const float*)d_in[7];
    const float* W2root = (const float*)d_in[8];
    const float* W3rel  = (const float*)d_in[9];
    const float* b3     = (const float*)d_in[10];
    const float* W3root = (const float*)d_in[11];
    const float* Wl     = (const float*)d_in[12];
    const float* bl     = (const float*)d_in[13];
    float* out = (float*)d_out;

    char* ws = (char*)d_ws;
    size_t off = 0;
    auto carve = [&](size_t bytes) -> void* {
        void* p = ws + off;
        off += (bytes + 255) & ~(size_t)255;
        return p;
    };
    int*            rowptr  = (int*)carve((size_t)(N_NODES + 1) * 4);
    int*            csr     = (int*)carve((size_t)(N_EDGES + 64) * 4);   // +64: chunk prefetch slack
    // meta block (single memset): deg[DEGPAD] + bsum[PADB] + psum[N_GRAPHS*DCH]
    int*            meta    = (int*)carve((size_t)DEGPAD * 4 + (size_t)PADB * 4 + (size_t)N_GRAPHS * DCH * 4);
    int*            deg     = meta;
    int*            bsum    = meta + DEGPAD;
    float*          psum    = (float*)(meta + DEGPAD + PADB);
    int*            cur     = (int*)carve((size_t)DEGPAD * 4);
    unsigned short* frag    = (unsigned short*)carve((size_t)3 * 8 * 8 * 64 * 8 * 2);
    unsigned short* B1      = (unsigned short*)carve((size_t)(N_NODES + 1) * DCH * 2);   // +1 zero row
    unsigned short* B2      = (unsigned short*)carve((size_t)(N_NODES + 1) * DCH * 2);   // +1 zero row

    hipMemsetAsync(meta, 0, (size_t)DEGPAD * 4 + (size_t)PADB * 4 + (size_t)N_GRAPHS * DCH * 4, stream);

    // direct CSR build: degrees -> rowptr/cursors -> scatter (+ prep merged)
    deg_kernel<<<782, 256, 0, stream>>>(dst, deg, bsum);
    rowcur_kernel<<<NBK, 256, 0, stream>>>(bsum, deg, rowptr, cur);
    scatPrep_kernel<<<1563 + 12549, 256, 0, stream>>>(src, dst, cur, csr,
                                                      x, B2, W1rel, W1root, W2rel, W2root, W3rel, W3root,
                                                      frag, B1 + (size_t)N_NODES * DCH, B2 + (size_t)N_NODES * DCH);

    const int layerGrid = N_NODES / 16;          // 6250, exact

    // fused layers (agg + gemm); ping-pong B2 -> B1 -> B2; layer 3 pools into psum
    layer_kernel<<<layerGrid, 256, 0, stream>>>(B2, rowptr, csr, frag,         b1, B1, batch, psum, 1);
    layer_kernel<<<layerGrid, 256, 0, stream>>>(B1, rowptr, csr, frag + 32768, b2, B2, batch, psum, 1);
    layer_kernel<<<layerGrid, 256, 0, stream>>>(B2, rowptr, csr, frag + 65536, b3, B1, batch, psum, 2);

    final_kernel<<<N_GRAPHS, 64, 0, stream>>>(psum, batch, Wl, bl, out);
}

// Round 9
// 381.493 us; speedup vs baseline: 1.4608x; 1.4608x over previous
//
#include <hip/hip_runtime.h>
#include <hip/hip_bf16.h>

#define N_NODES  100000
#define N_EDGES  1600000
#define N_GRAPHS 256
#define DCH      128
#define DOUT     64
#define NB       391      // buckets = ceil(100000/256)
#define PADB     512
#define SLACK    4608     // per-bucket region capacity (mean 4096 + 8 sigma)
#define CHUNK    2048     // edges per binA block
#define NBINA    782      // ceil(N_EDGES / CHUNK)

typedef short v8s __attribute__((ext_vector_type(8)));
typedef float v4f __attribute__((ext_vector_type(4)));

static __device__ __forceinline__ float bf2f(unsigned short u) {
    unsigned int x = ((unsigned int)u) << 16;
    return __builtin_bit_cast(float, x);
}
static __device__ __forceinline__ unsigned short f2bf(float f) {
    unsigned int x = __builtin_bit_cast(unsigned int, f);
    unsigned int r = (x + 0x7fffu + ((x >> 16) & 1u)) >> 16;
    return (unsigned short)r;
}
static __device__ __forceinline__ int clampi(int v, int lo, int hi) {
    return v < lo ? lo : (v > hi ? hi : v);
}

// ---------------- binA: partition edges into dst>>8 buckets (packed 4B region) ----------------
// Region entry = (src<<8) | (dst&255): halves region write vs uint2 (r8 lesson: keep
// writes in coalesced bucket runs; packing shrinks traffic without breaking locality).
__global__ void __launch_bounds__(256) binA_kernel(const int* __restrict__ src, const int* __restrict__ dst,
                                                   int* __restrict__ gcur, unsigned* __restrict__ region) {
    __shared__ uint2 stage[CHUNK];          // 16 KB (full pairs: bucket id needed at write)
    __shared__ int hcnt[PADB], hcnt2[PADB], hoff[PADB], garr[PADB];
    __shared__ int s2[256];
    int tid = threadIdx.x;
    int e0  = blockIdx.x * CHUNK;
    int nedge = N_EDGES - e0; if (nedge > CHUNK) nedge = CHUNK;

    for (int b = tid; b < PADB; b += 256) { hcnt[b] = 0; hcnt2[b] = 0; }
    __syncthreads();

    int es[CHUNK / 256], ed[CHUNK / 256];
    #pragma unroll
    for (int j = 0; j < CHUNK / 256; j++) {
        int e = e0 + j * 256 + tid;
        if (e < N_EDGES) {
            es[j] = clampi(src[e], 0, N_NODES - 1);
            ed[j] = clampi(dst[e], 0, N_NODES - 1);
            atomicAdd(&hcnt[ed[j] >> 8], 1);
        } else { es[j] = -1; ed[j] = 0; }
    }
    __syncthreads();

    int v0 = hcnt[2 * tid], v1 = hcnt[2 * tid + 1];
    s2[tid] = v0 + v1; __syncthreads();
    for (int off = 1; off < 256; off <<= 1) {
        int xx = (tid >= off) ? s2[tid - off] : 0;
        __syncthreads();
        s2[tid] += xx;
        __syncthreads();
    }
    int excl = s2[tid] - (v0 + v1);
    hoff[2 * tid] = excl; hoff[2 * tid + 1] = excl + v0;
    __syncthreads();

    for (int b = tid; b < NB; b += 256) {
        int c = hcnt[b];
        garr[b] = b * SLACK + ((c > 0) ? atomicAdd(&gcur[b], c) : 0);
    }
    __syncthreads();

    #pragma unroll
    for (int j = 0; j < CHUNK / 256; j++) {
        if (es[j] >= 0) {
            int b = ed[j] >> 8;
            int pos = atomicAdd(&hcnt2[b], 1) + hoff[b];
            stage[pos] = (uint2){(unsigned)es[j], (unsigned)ed[j]};
        }
    }
    __syncthreads();

    for (int i = tid; i < nedge; i += 256) {
        uint2 en = stage[i];
        int b = (int)(en.y >> 8);
        int gpos = garr[b] + (i - hoff[b]);
        if (gpos < (b + 1) * SLACK)
            region[gpos] = (en.x << 8) | (en.y & 255u);   // packed: src<<8 | loc
    }
}

// ---------------- binFinish (bid < NB) + prep (cvt/wfrag/zero rows), one dispatch ----------------
// r7 ran binFinish ALONE at 391 blocks (~1.5/CU, machine idle). Merging prep's 12549
// traffic-bound blocks into the same dispatch fills the idle CUs; binFinish blocks are
// first (low blockIdx) so they start immediately.
__global__ void __launch_bounds__(256) binFinishPrep_kernel(
    const unsigned* __restrict__ region, const int* __restrict__ gcur,
    int* __restrict__ rowptr, int* __restrict__ csr,
    const float* __restrict__ x, unsigned short* __restrict__ B2,
    const float* __restrict__ W1rel, const float* __restrict__ W1root,
    const float* __restrict__ W2rel, const float* __restrict__ W2root,
    const float* __restrict__ W3rel, const float* __restrict__ W3root,
    unsigned short* __restrict__ frag,
    unsigned short* __restrict__ z1, unsigned short* __restrict__ z2)
{
    __shared__ int h[256], sc[256], cur[256], s2[256], hoff[PADB];
    int tid = threadIdx.x;

    if (blockIdx.x >= NB) {
        // ---------------- prep part ----------------
        int bid = blockIdx.x - NB;
        if (bid < 12500) {                   // cvt: 12500*256*4 == N_NODES*DCH exactly
            size_t i = ((size_t)bid * 256 + tid) * 4;
            float4 f = *reinterpret_cast<const float4*>(x + i);
            uint2 o;
            o.x = ((unsigned)f2bf(f.y) << 16) | (unsigned)f2bf(f.x);
            o.y = ((unsigned)f2bf(f.w) << 16) | (unsigned)f2bf(f.z);
            *reinterpret_cast<uint2*>(B2 + i) = o;
        } else if (bid < 12548) {            // wfrag: 48*256 == 12288 == 3*8*8*64
            int gid = (bid - 12500) * 256 + tid;
            int lane = gid & 63;
            int nt   = (gid >> 6) & 7;
            int kt   = (gid >> 9) & 7;
            int L    = gid >> 12;
            const float* rel  = (L == 0) ? W1rel  : (L == 1) ? W2rel  : W3rel;
            const float* root = (L == 0) ? W1root : (L == 1) ? W2root : W3root;
            int n  = nt * 16 + (lane & 15);
            int k0 = kt * 32 + (lane >> 4) * 8;
            unsigned short o[8];
            #pragma unroll
            for (int j = 0; j < 8; j++) {
                int k = k0 + j;
                float w = (k < 128) ? rel[k * 128 + n] : root[(k - 128) * 128 + n];
                o[j] = f2bf(w);
            }
            uint4 u;
            u.x = (unsigned)o[0] | ((unsigned)o[1] << 16);
            u.y = (unsigned)o[2] | ((unsigned)o[3] << 16);
            u.z = (unsigned)o[4] | ((unsigned)o[5] << 16);
            u.w = (unsigned)o[6] | ((unsigned)o[7] << 16);
            *reinterpret_cast<uint4*>(frag + (size_t)gid * 8) = u;
        } else {                             // zero rows (gather target for padded lanes)
            if (tid < 64)       reinterpret_cast<unsigned*>(z1)[tid] = 0;
            else if (tid < 128) reinterpret_cast<unsigned*>(z2)[tid - 64] = 0;
        }
        return;
    }

    // ---------------- binFinish part ----------------
    int b = blockIdx.x;
    int c0 = gcur[2 * tid];     if (c0 > SLACK) c0 = SLACK;
    int c1 = gcur[2 * tid + 1]; if (c1 > SLACK) c1 = SLACK;
    s2[tid] = c0 + c1;
    h[tid] = 0;
    __syncthreads();
    for (int off = 1; off < 256; off <<= 1) {
        int xx = (tid >= off) ? s2[tid - off] : 0;
        __syncthreads();
        s2[tid] += xx;
        __syncthreads();
    }
    int excl = s2[tid] - (c0 + c1);
    hoff[2 * tid] = excl; hoff[2 * tid + 1] = excl + c0;
    __syncthreads();
    if (b == 0 && tid == 255) rowptr[N_NODES] = s2[255];
    int base = hoff[b];
    int size = gcur[b]; if (size > SLACK) size = SLACK;
    int node0 = b * 256;
    // degree histogram (packed entries: loc = en & 255)
    for (int j = tid; j < size; j += 256) {
        unsigned loc = region[b * SLACK + j] & 255u;
        atomicAdd(&h[loc], 1);
    }
    __syncthreads();
    int v = h[tid]; sc[tid] = v; __syncthreads();
    for (int off = 1; off < 256; off <<= 1) {
        int xx = (tid >= off) ? sc[tid - off] : 0;
        __syncthreads();
        sc[tid] += xx;
        __syncthreads();
    }
    int myptr = base + sc[tid] - v;
    int node = node0 + tid;
    if (node < N_NODES) rowptr[node] = myptr;
    cur[tid] = myptr;
    __syncthreads();
    // scatter into csr (writes stay inside this bucket's ~16KB csr window)
    for (int j = tid; j < size; j += 256) {
        unsigned en = region[b * SLACK + j];
        unsigned loc = en & 255u;
        int p = atomicAdd(&cur[loc], 1);
        if (p >= 0 && p < N_EDGES) csr[p] = (int)(en >> 8);
    }
}

// ---------------- fused layer: block-level agg (4 waves x 4 nodes) + MFMA tail ----------------
// Byte-identical to r7 (best measured: 74 us/layer).
__global__ void __launch_bounds__(256, 6) layer_kernel(
    const unsigned short* __restrict__ hin,   // N_NODES+1 rows; row N_NODES is zero
    const int* __restrict__ rowptr, const int* __restrict__ csr,
    const unsigned short* __restrict__ frag, const float* __restrict__ bias,
    unsigned short* __restrict__ hout,        // != hin (ping-pong; unused for mode 2)
    const int* __restrict__ batch, float* __restrict__ psum, int mode)
{
    __shared__ __attribute__((aligned(16))) unsigned short As[16 * DCH];  // 4 KB
    const int wave = threadIdx.x >> 6;
    const int lane = threadIdx.x & 63;
    const int l16  = lane & 15;
    const int quad = lane >> 4;
    const int base = blockIdx.x * 16;
    char* Asb = reinterpret_cast<char*>(As);

    // ---------- aggregation: 4 independent per-node loops ----------
    #pragma unroll
    for (int k = 0; k < 4; k++) {
        const int row  = wave * 4 + k;
        const int node = base + row;
        const int r0 = rowptr[node];          // wave-uniform -> scalar loads
        const int r1 = rowptr[node + 1];
        float a0 = 0.f, a1 = 0.f;
        int t = csr[r0 + l16];                // csr over-allocated: overread safe
        for (int c = r0; c < r1; c += 16) {
            int tn = csr[c + 16 + l16];       // prefetch next chunk
            int idx = (c + l16 < r1) ? t : N_NODES;
            #pragma unroll
            for (int j = 0; j < 16; j++) {
                int s = __builtin_amdgcn_readlane(idx, j);   // SGPR row index -> saddr gather
                unsigned v = *reinterpret_cast<const unsigned*>(hin + (size_t)s * DCH + lane * 2);
                a0 += bf2f((unsigned short)(v & 0xffffu));   // padded lanes hit the zero row
                a1 += bf2f((unsigned short)(v >> 16));
            }
            t = tn;
        }
        int deg = r1 - r0;
        float inv = 1.0f / (float)(deg > 1 ? deg : 1);
        unsigned o = ((unsigned)f2bf(a1 * inv) << 16) | (unsigned)f2bf(a0 * inv);
        *reinterpret_cast<unsigned*>(Asb + row * 256 + ((lane * 4) ^ ((row & 7) << 4))) = o;
    }
    __syncthreads();

    // ---------- MFMA tail: wave w -> nt = 2w, 2w+1 ----------
    const int nt0 = wave * 2;
    v4f acc0 = (v4f){0.f, 0.f, 0.f, 0.f};
    v4f acc1 = (v4f){0.f, 0.f, 0.f, 0.f};
    #pragma unroll
    for (int kt = 0; kt < 8; kt++) {
        v8s av;
        if (kt < 4) {
            int co = (kt * 64 + quad * 16) ^ ((l16 & 7) << 4);
            av = *reinterpret_cast<const v8s*>(Asb + l16 * 256 + co);
        } else {
            int ak = (kt - 4) * 32 + quad * 8;
            av = *reinterpret_cast<const v8s*>(hin + (size_t)(base + l16) * DCH + ak);
        }
        v8s b0 = *reinterpret_cast<const v8s*>(frag + (((size_t)(kt * 8 + nt0)) * 64 + lane) * 8);
        v8s b1 = *reinterpret_cast<const v8s*>(frag + (((size_t)(kt * 8 + nt0 + 1)) * 64 + lane) * 8);
        acc0 = __builtin_amdgcn_mfma_f32_16x16x32_bf16(av, b0, acc0, 0, 0, 0);
        acc1 = __builtin_amdgcn_mfma_f32_16x16x32_bf16(av, b1, acc1, 0, 0, 0);
    }

    const int n0 = nt0 * 16 + l16;
    const int n1 = n0 + 16;
    const float bv0 = bias[n0];
    const float bv1 = bias[n1];

    if (mode != 2) {
        #pragma unroll
        for (int r = 0; r < 4; r++) {
            int row = base + quad * 4 + r;    // always < N_NODES (exact tiling)
            float x0 = acc0[r] + bv0;
            float x1 = acc1[r] + bv1;
            if (mode == 1) { x0 = fmaxf(x0, 0.f); x1 = fmaxf(x1, 0.f); }
            hout[(size_t)row * DCH + n0] = f2bf(x0);
            hout[(size_t)row * DCH + n1] = f2bf(x1);
        }
    } else {
        // pooled epilogue: per-graph column sums (mean + matvec in final_kernel)
        bool fast = (batch[base] == batch[base + 15]);
        if (fast) {
            int g = batch[base];              // all 16 rows same graph (~94% of blocks)
            float s0 = acc0[0] + acc0[1] + acc0[2] + acc0[3] + 4.0f * bv0;
            float s1 = acc1[0] + acc1[1] + acc1[2] + acc1[3] + 4.0f * bv1;
            s0 += __shfl_xor(s0, 16); s0 += __shfl_xor(s0, 32);
            s1 += __shfl_xor(s1, 16); s1 += __shfl_xor(s1, 32);
            if (quad == 0) {
                atomicAdd(&psum[g * DCH + n0], s0);
                atomicAdd(&psum[g * DCH + n1], s1);
            }
        } else {
            int g[4];
            #pragma unroll
            for (int r = 0; r < 4; r++) g[r] = batch[base + quad * 4 + r];
            float s0 = 0.f, s1 = 0.f; int cg = -1;
            #pragma unroll
            for (int r = 0; r < 4; r++) {
                if (g[r] != cg) {
                    if (cg >= 0) {
                        atomicAdd(&psum[cg * DCH + n0], s0);
                        atomicAdd(&psum[cg * DCH + n1], s1);
                    }
                    s0 = 0.f; s1 = 0.f; cg = g[r];
                }
                s0 += acc0[r] + bv0;
                s1 += acc1[r] + bv1;
            }
            if (cg >= 0) {
                atomicAdd(&psum[cg * DCH + n0], s0);
                atomicAdd(&psum[cg * DCH + n1], s1);
            }
        }
    }
}

// ---------------- final: out[g] = (psum[g]/cnt_g) @ Wl + bl ----------------
static __device__ __forceinline__ int lowerb(const int* __restrict__ a, int n, int key) {
    int lo = 0, hi = n;
    while (lo < hi) { int mid = (lo + hi) >> 1; if (a[mid] < key) lo = mid + 1; else hi = mid; }
    return lo;
}

__global__ void __launch_bounds__(64) final_kernel(const float* __restrict__ psum,
                                                   const int* __restrict__ batch,
                                                   const float* __restrict__ Wl, const float* __restrict__ bl,
                                                   float* __restrict__ out) {
    __shared__ float ps[DCH];
    __shared__ int bounds[2];
    int g = blockIdx.x, tid = threadIdx.x;
    if (tid == 0) {
        bounds[0] = lowerb(batch, N_NODES, g);
        bounds[1] = lowerb(batch, N_NODES, g + 1);
    }
    __syncthreads();
    int cnt = bounds[1] - bounds[0];
    float inv = 1.0f / (float)(cnt > 1 ? cnt : 1);
    ps[tid] = psum[g * DCH + tid] * inv;
    ps[tid + 64] = psum[g * DCH + tid + 64] * inv;
    __syncthreads();
    float o = 0.f;
    #pragma unroll 4
    for (int c = 0; c < DCH; c++) o += ps[c] * Wl[c * DOUT + tid];
    out[g * DOUT + tid] = o + bl[tid];
}

extern "C" void kernel_launch(void* const* d_in, const int* in_sizes, int n_in,
                              void* d_out, int out_size, void* d_ws, size_t ws_size,
                              hipStream_t stream) {
    const float* x     = (const float*)d_in[0];
    const int*   edge  = (const int*)d_in[1];
    const int*   src   = edge;
    const int*   dst   = edge + N_EDGES;
    const int*   batch = (const int*)d_in[2];
    const float* W1rel  = (const float*)d_in[3];
    const float* b1     = (const float*)d_in[4];
    const float* W1root = (const float*)d_in[5];
    const float* W2rel  = (const float*)d_in[6];
    const float* b2     = (const float*)d_in[7];
    const float* W2root = (const float*)d_in[8];
    const float* W3rel  = (const float*)d_in[9];
    const float* b3     = (const float*)d_in[10];
    const float* W3root = (const float*)d_in[11];
    const float* Wl     = (const float*)d_in[12];
    const float* bl     = (const float*)d_in[13];
    float* out = (float*)d_out;

    char* ws = (char*)d_ws;
    size_t off = 0;
    auto carve = [&](size_t bytes) -> void* {
        void* p = ws + off;
        off += (bytes + 255) & ~(size_t)255;
        return p;
    };
    int*            rowptr  = (int*)carve((size_t)(N_NODES + 1) * 4);
    int*            csr     = (int*)carve((size_t)(N_EDGES + 64) * 4);   // +64: chunk prefetch slack
    int*            gcur    = (int*)carve((size_t)PADB * 4 + (size_t)N_GRAPHS * DCH * 4); // gcur + psum
    float*          psum    = (float*)(gcur + PADB);
    unsigned short* frag    = (unsigned short*)carve((size_t)3 * 8 * 8 * 64 * 8 * 2);
    unsigned short* B1      = (unsigned short*)carve((size_t)(N_NODES + 1) * DCH * 2);   // +1 zero row
    unsigned short* B2      = (unsigned short*)carve((size_t)(N_NODES + 1) * DCH * 2);   // +1 zero row
    unsigned*       region  = (unsigned*)B1;   // packed: 391*4608*4 = 7.2 MB <= 25.6 MB

    hipMemsetAsync(gcur, 0, (size_t)PADB * 4 + (size_t)N_GRAPHS * DCH * 4, stream);

    // CSR build: binA alone, then binFinish + prep merged (prep fills the idle CUs
    // behind binFinish's 391 blocks; binFinish blocks are first so they start at t0)
    binA_kernel<<<NBINA, 256, 0, stream>>>(src, dst, gcur, region);
    binFinishPrep_kernel<<<NB + 12549, 256, 0, stream>>>(region, gcur, rowptr, csr,
                                                         x, B2, W1rel, W1root, W2rel, W2root, W3rel, W3root,
                                                         frag, B1 + (size_t)N_NODES * DCH, B2 + (size_t)N_NODES * DCH);

    const int layerGrid = N_NODES / 16;          // 6250, exact

    // fused layers (agg + gemm); ping-pong B2 -> B1 -> B2; layer 3 pools into psum
    layer_kernel<<<layerGrid, 256, 0, stream>>>(B2, rowptr, csr, frag,         b1, B1, batch, psum, 1);
    layer_kernel<<<layerGrid, 256, 0, stream>>>(B1, rowptr, csr, frag + 32768, b2, B2, batch, psum, 1);
    layer_kernel<<<layerGrid, 256, 0, stream>>>(B2, rowptr, csr, frag + 65536, b3, B1, batch, psum, 2);

    final_kernel<<<N_GRAPHS, 64, 0, stream>>>(psum, batch, Wl, bl, out);
}